// Round 9
// baseline (62.334 us; speedup 1.0000x reference)
//
#include <hip/hip_runtime.h>

// Problem constants
#define NB   64    // B
#define DD   256   // D
#define TT   512   // T
#define KK   512   // K

typedef short bf8 __attribute__((ext_vector_type(8)));   // 8 x bf16 bits (4 VGPR)
typedef float f4  __attribute__((ext_vector_type(4)));

union BF8U { bf8 v; unsigned u[4]; };

// D = A*B + D  (A rows = codewords k, B cols = t, reduction = d)
#define MFMA(accv, va, vb) \
  asm("v_mfma_f32_16x16x32_bf16 %0, %1, %2, %0" : "+v"(accv) : "v"(va), "v"(vb))

#define ACCROW(acc, kt) \
    "+v"(acc[kt][0]), "+v"(acc[kt][1]), "+v"(acc[kt][2]), "+v"(acc[kt][3]), \
    "+v"(acc[kt][4]), "+v"(acc[kt][5]), "+v"(acc[kt][6]), "+v"(acc[kt][7])
#define ACCLIST8(acc) ACCROW(acc,0), ACCROW(acc,1), ACCROW(acc,2), ACCROW(acc,3)

// pack two fp32 -> (bf16(x1)<<16)|bf16(x0), round-half-up, via v_perm_b32
__device__ inline unsigned pkbf(float x0, float x1, unsigned sel) {
  const unsigned a = __float_as_uint(x0) + 0x8000u;
  const unsigned b = __float_as_uint(x1) + 0x8000u;
  unsigned d;
  asm("v_perm_b32 %0, %1, %2, %3" : "=v"(d) : "v"(b), "v"(a), "s"(sel));
  return d;
}

// lgkmcnt-only barrier: waits LDS writes, does NOT drain in-flight global loads
__device__ inline void lgkm_barrier() {
  asm volatile("s_waitcnt lgkmcnt(0)" ::: "memory");
  __builtin_amdgcn_s_barrier();
  asm volatile("" ::: "memory");
}

// ---------------------------------------------------------------------------
// SINGLE fused kernel (counter zeroed by an async-memset node each launch).
// Grid 256 x 512 threads, one block per (b, t-tile 128).
//  - rec/Dhat: per-block 1/256 slice.
//  - H staging: thread (q,tcol) gathers its column slices with coalesced
//    scalar loads; second d-half loads fly under MFMA half 1 (lgkm-only
//    barriers keep them in flight).
//  - A operand: converted on the fly from fp32 M (L2/L3-resident; every
//    block reads all of M) -> no cross-block handoff. mnorm in-register.
//  - Last-finishing block (counter==255, provably zero-started) sums the
//    256 release-published block contributions -> out[0].
// ---------------------------------------------------------------------------
__global__ __launch_bounds__(512, 2) void edm_all(
    const float* __restrict__ H, const float* __restrict__ M,
    const float4* __restrict__ Xh, const float4* __restrict__ X,
    const float4* __restrict__ Dh,
    float* __restrict__ d2part, unsigned* __restrict__ counter,
    float* __restrict__ out) {
  __shared__ __align__(16) unsigned short Hbf[128 * 256];  // [t][d] bf16, swizzled
  __shared__ __align__(16) float mn_lds[512];
  __shared__ float hsumP[4][128];
  __shared__ float wmin[8][128];
  __shared__ float recw[4], dhw[4];
  __shared__ float red[12];
  __shared__ float bsum[2];
  __shared__ int   islast;

  const int tid  = threadIdx.x;
  const int bid  = blockIdx.x;
  const int wv   = tid >> 6;       // wave 0..7
  const int l    = tid & 63;
  const int tcol = tid & 127;      // owned t column
  const int q    = tid >> 7;       // 0..3
  const int r16  = l & 15;
  const int g    = l >> 4;
  const unsigned sel = 0x07060302u;

  const int b  = bid >> 2;
  const int t0 = (bid & 3) << 7;
  const float* Hcol = H + (size_t)b * DD * TT + t0 + tcol;

  // ---- rec / Dhat slice (1/256 of the problem per block) ----
  float recv = 0.f, dhv = 0.f;
  if (tid < 256) {
    const float4 a = Xh[bid * 256 + tid];
    const float4 c = X[bid * 256 + tid];
    const float e0 = a.x - c.x, e1 = a.y - c.y, e2 = a.z - c.z, e3 = a.w - c.w;
    recv = e0 * e0 + e1 * e1 + e2 * e2 + e3 * e3;
    if (tid < 32) {
      const float4 dd = Dh[bid * 32 + tid];
      dhv = dd.x + dd.y + dd.z + dd.w;
    }
  }

  // ---- H staging: d = r*64 + q*16 + j ----
  char* rowp = (char*)Hbf + tcol * 512;
  const int swz = (tcol & 7) << 4;
  float hacc = 0.f;

  #define PACKSTORE(xarr, dbyte)                                              \
    { unsigned pk[8];                                                         \
      _Pragma("unroll")                                                       \
      for (int e = 0; e < 8; ++e) {                                           \
        hacc += xarr[2*e] * xarr[2*e] + xarr[2*e+1] * xarr[2*e+1];            \
        pk[e] = pkbf(xarr[2*e], xarr[2*e+1], sel);                            \
      }                                                                       \
      *(uint4*)(rowp + (((dbyte) +  0) ^ swz)) = make_uint4(pk[0],pk[1],pk[2],pk[3]); \
      *(uint4*)(rowp + (((dbyte) + 16) ^ swz)) = make_uint4(pk[4],pk[5],pk[6],pk[7]); }

  float xA[16], xB[16], xC[16], xD[16];
  #pragma unroll
  for (int j = 0; j < 16; ++j) xA[j] = Hcol[(size_t)(      q * 16 + j) * TT];
  #pragma unroll
  for (int j = 0; j < 16; ++j) xB[j] = Hcol[(size_t)( 64 + q * 16 + j) * TT];
  PACKSTORE(xA, q * 32)
  PACKSTORE(xB, 128 + q * 32)
  // issue second-half loads now; they fly under MFMA half 1
  #pragma unroll
  for (int j = 0; j < 16; ++j) xC[j] = Hcol[(size_t)(128 + q * 16 + j) * TT];
  #pragma unroll
  for (int j = 0; j < 16; ++j) xD[j] = Hcol[(size_t)(192 + q * 16 + j) * TT];

  f4 acc[4][8];
  #pragma unroll
  for (int kt = 0; kt < 4; ++kt)
    #pragma unroll
    for (int tn = 0; tn < 8; ++tn)
      acc[kt][tn] = (f4){0.f, 0.f, 0.f, 0.f};
  asm volatile("s_nop 1" : ACCLIST8(acc));   // VALU-write -> MFMA-read-C guard

  lgkm_barrier();                            // Hbf d<128 published; xC/xD in flight

  // ---- MFMA with on-the-fly A conversion; wave wv owns k in [wv*64, +64) ----
  const float* Mb = M + (size_t)(g * 8) * KK + wv * 64 + r16;
  float msq[4] = {0.f, 0.f, 0.f, 0.f};

  #define MFMA_HALF(h)                                                        \
    _Pragma("unroll")                                                         \
    for (int s = 0; s < 4; ++s) {                                             \
      const int ds = (h) * 4 + s;                                             \
      BF8U afr[4];                                                            \
      _Pragma("unroll")                                                       \
      for (int kt = 0; kt < 4; ++kt) {                                        \
        float mx[8];                                                          \
        _Pragma("unroll")                                                     \
        for (int j = 0; j < 8; ++j)                                           \
          mx[j] = Mb[(size_t)(ds * 32 + j) * KK + kt * 16];                   \
        _Pragma("unroll")                                                     \
        for (int j = 0; j < 8; ++j) msq[kt] += mx[j] * mx[j];                 \
        afr[kt].u[0] = pkbf(mx[0], mx[1], sel);                               \
        afr[kt].u[1] = pkbf(mx[2], mx[3], sel);                               \
        afr[kt].u[2] = pkbf(mx[4], mx[5], sel);                               \
        afr[kt].u[3] = pkbf(mx[6], mx[7], sel);                               \
      }                                                                       \
      asm volatile("s_nop 2" : "+v"(afr[0].v), "+v"(afr[1].v),                \
                               "+v"(afr[2].v), "+v"(afr[3].v));               \
      _Pragma("unroll")                                                       \
      for (int tn = 0; tn < 8; ++tn) {                                        \
        const int t = tn * 16 + r16;                                          \
        const bf8 bfr = *(const bf8*)((const char*)Hbf + t * 512 +            \
                            ((ds * 64 + g * 16) ^ ((t & 7) << 4)));           \
        MFMA(acc[0][tn], afr[0].v, bfr);                                      \
        MFMA(acc[1][tn], afr[1].v, bfr);                                      \
        MFMA(acc[2][tn], afr[2].v, bfr);                                      \
        MFMA(acc[3][tn], afr[3].v, bfr);                                      \
      }                                                                       \
    }

  MFMA_HALF(0)

  // pack/store second d-half (waits its loads here), publish, MFMA half 2
  PACKSTORE(xC, 256 + q * 32)
  PACKSTORE(xD, 384 + q * 32)
  hsumP[q][tcol] = hacc;
  lgkm_barrier();                            // Hbf d>=128 published

  MFMA_HALF(1)
  asm volatile("s_nop 7\n\ts_nop 7" : ACCLIST8(acc));  // MFMA-write -> VALU guard

  // ---- mnorm: reduce msq over lane-groups g (disjoint d, same k) ----
  #pragma unroll
  for (int kt = 0; kt < 4; ++kt) {
    float v = msq[kt];
    v += __shfl_xor(v, 16);
    v += __shfl_xor(v, 32);
    if (g == 0) mn_lds[wv * 64 + kt * 16 + r16] = v;
  }
  // rec/Dhat per-wave reduce (waves 0..3 hold data)
  {
    float rsum = recv, dsum = dhv;
    #pragma unroll
    for (int off = 32; off > 0; off >>= 1) {
      rsum += __shfl_down(rsum, off);
      dsum += __shfl_down(dsum, off);
    }
    if (tid < 256 && l == 0) { recw[wv] = rsum; dhw[wv] = dsum; }
  }
  __syncthreads();                           // publish mn_lds, recw/dhw, hsumP

  // ---- fold: k = wv*64 + kt*16 + 4*g + rr (C/D map col=l&15, row=4g+reg) ----
  float rmin[8] = {3.0e38f, 3.0e38f, 3.0e38f, 3.0e38f,
                   3.0e38f, 3.0e38f, 3.0e38f, 3.0e38f};
  #pragma unroll
  for (int kt = 0; kt < 4; ++kt) {
    const f4 mn = *(const f4*)&mn_lds[wv * 64 + kt * 16 + g * 4];
    #pragma unroll
    for (int tn = 0; tn < 8; ++tn) {
      #pragma unroll
      for (int rr = 0; rr < 4; ++rr)
        rmin[tn] = fminf(rmin[tn], mn[rr] - 2.f * acc[kt][tn][rr]);
    }
  }
  #pragma unroll
  for (int tn = 0; tn < 8; ++tn) {
    rmin[tn] = fminf(rmin[tn], __shfl_xor(rmin[tn], 16));
    rmin[tn] = fminf(rmin[tn], __shfl_xor(rmin[tn], 32));
  }
  if (g == 0) {
    #pragma unroll
    for (int tn = 0; tn < 8; ++tn) wmin[wv][tn * 16 + r16] = rmin[tn];
  }
  __syncthreads();

  if (tid < 128) {
    float m = wmin[0][tid];
    #pragma unroll
    for (int w = 1; w < 8; ++w) m = fminf(m, wmin[w][tid]);
    float v = m + hsumP[0][tid] + hsumP[1][tid] + hsumP[2][tid] + hsumP[3][tid];
    #pragma unroll
    for (int off = 32; off > 0; off >>= 1) v += __shfl_down(v, off);
    if ((tid & 63) == 0) bsum[tid >> 6] = v;
  }
  __syncthreads();

  if (tid == 0) {
    const float rsumT = recw[0] + recw[1] + recw[2] + recw[3];
    const float dsumT = dhw[0] + dhw[1] + dhw[2] + dhw[3];
    // block contribution, pre-scaled:
    // d2: 0.25*2/8388608 = 1/16777216 ; rec: /262144 ; Dhat: -0.1/32768
    const float contrib = (bsum[0] + bsum[1]) * (1.f / 16777216.f)
                        + rsumT * (1.f / 262144.f)
                        - 0.1f * dsumT * (1.f / 32768.f);
    __hip_atomic_store(&d2part[bid], contrib, __ATOMIC_RELEASE,
                       __HIP_MEMORY_SCOPE_AGENT);
    const unsigned old = __hip_atomic_fetch_add(counter, 1u, __ATOMIC_ACQ_REL,
                                                __HIP_MEMORY_SCOPE_AGENT);
    islast = (old == 255u) ? 1 : 0;          // counter memset to 0 every launch
  }
  __syncthreads();

  if (islast) {
    float a = 0.f;
    if (tid < 256)
      a = __hip_atomic_load(&d2part[tid], __ATOMIC_RELAXED,
                            __HIP_MEMORY_SCOPE_AGENT);
    #pragma unroll
    for (int off = 32; off > 0; off >>= 1) a += __shfl_down(a, off);
    if (tid < 256 && l == 0) red[wv] = a;
    __syncthreads();
    if (tid == 0) out[0] = red[0] + red[1] + red[2] + red[3];
  }
}

extern "C" void kernel_launch(void* const* d_in, const int* in_sizes, int n_in,
                              void* d_out, int out_size, void* d_ws, size_t ws_size,
                              hipStream_t stream) {
  const float* Xh = (const float*)d_in[0];   // [64,8,512]
  const float* X  = (const float*)d_in[1];   // [64,8,512]
  const float* H  = (const float*)d_in[2];   // [64,256,512]
  const float* M  = (const float*)d_in[3];   // [256,512]
  const float* Dh = (const float*)d_in[4];   // [64,512]
  float* out = (float*)d_out;

  float* d2part     = (float*)d_ws;              // 256 f
  unsigned* counter = (unsigned*)(d2part + 256); // 1 u32

  // Provably zero-started completion counter each launch (graph-capturable).
  hipMemsetAsync(counter, 0, sizeof(unsigned), stream);

  edm_all<<<NB * (TT / 128), 512, 0, stream>>>(
      H, M, (const float4*)Xh, (const float4*)X, (const float4*)Dh,
      d2part, counter, out);
}

// Round 10
// 28.391 us; speedup vs baseline: 2.1955x; 2.1955x over previous
//
#include <hip/hip_runtime.h>

// Problem constants
#define NB   64    // B
#define DD   256   // D
#define TT   512   // T
#define KK   512   // K

typedef short bf8 __attribute__((ext_vector_type(8)));   // 8 x bf16 bits (4 VGPR)
typedef float f4  __attribute__((ext_vector_type(4)));

__device__ inline unsigned f2bf(float x) {
  unsigned u = __float_as_uint(x);
  u += 0x7FFFu + ((u >> 16) & 1u);   // round-to-nearest-even
  return u >> 16;
}

// pack two fp32 -> (bf16(x1)<<16)|bf16(x0), round-half-up, via v_perm_b32
__device__ inline unsigned pkbf(float x0, float x1, unsigned sel) {
  const unsigned a = __float_as_uint(x0) + 0x8000u;
  const unsigned b = __float_as_uint(x1) + 0x8000u;
  unsigned d;
  asm("v_perm_b32 %0, %1, %2, %3" : "=v"(d) : "v"(b), "v"(a), "s"(sel));
  return d;
}

// D = A*B + D  (A rows = codewords k, B cols = t, reduction = d)
#define MFMA(accv, va, vb) \
  asm("v_mfma_f32_16x16x32_bf16 %0, %1, %2, %0" : "+v"(accv) : "v"(va), "v"(vb))

#define ACCROW(acc, kt) \
    "+v"(acc[kt][0]), "+v"(acc[kt][1]), "+v"(acc[kt][2]), "+v"(acc[kt][3]), \
    "+v"(acc[kt][4]), "+v"(acc[kt][5]), "+v"(acc[kt][6]), "+v"(acc[kt][7])
#define ACCLIST8(acc) ACCROW(acc,0), ACCROW(acc,1), ACCROW(acc,2), ACCROW(acc,3)

// ---------------------------------------------------------------------------
// Kernel 1 (prep) — verified R6/R7 version:
//   blocks 0..7  : M [D][K] fp32 -> MtF fragment-ordered bf16 + mnorm[k].
//     MtF[((k16*8+ds)*64 + l)*8 + j] = bf16(M[ds*32+(l>>4)*8+j][k16*16+(l&15)])
//   blocks 8..71 : rec partial sums (Xhat-X)^2 and Dhat partial sums.
//   block 0 zeroes the completion counter (kernel boundary publishes all).
// ---------------------------------------------------------------------------
__global__ __launch_bounds__(256) void edm_prep(
    const float* __restrict__ M, const float4* __restrict__ Xh,
    const float4* __restrict__ X, const float4* __restrict__ Dh,
    unsigned short* __restrict__ MtF, float* __restrict__ mnorm,
    float* __restrict__ recp, float* __restrict__ dhp,
    unsigned* __restrict__ counter) {
  __shared__ __align__(16) float tile[DD][68];
  __shared__ float pn[4][64];
  __shared__ float ps[8];

  const int bid  = blockIdx.x;
  const int tid  = threadIdx.x;
  const int lane = tid & 63;
  const int q    = tid >> 6;

  if (bid == 0 && tid == 0) *counter = 0u;

  if (bid < 8) {
    #pragma unroll
    for (int it = 0; it < 16; ++it) {
      const int d  = q * 64 + it * 4 + (lane >> 4);
      const int kc = (lane & 15) << 2;
      *(float4*)&tile[d][kc] = *(const float4*)(M + (size_t)d * KK + bid * 64 + kc);
    }
    __syncthreads();
    const int k    = bid * 64 + lane;
    const int k16  = k >> 4;
    const int r16k = k & 15;
    float s = 0.f;
    #pragma unroll
    for (int dsl = 0; dsl < 2; ++dsl) {          // thread owns d in [q*64, +64)
      const int ds = q * 2 + dsl;
      #pragma unroll
      for (int g = 0; g < 4; ++g) {
        unsigned pk[4];
        #pragma unroll
        for (int e = 0; e < 4; ++e) {
          const float x0 = tile[ds * 32 + g * 8 + 2 * e + 0][lane];
          const float x1 = tile[ds * 32 + g * 8 + 2 * e + 1][lane];
          s += x0 * x0 + x1 * x1;
          pk[e] = f2bf(x0) | (f2bf(x1) << 16);
        }
        *(uint4*)(MtF + ((size_t)(k16 * 8 + ds) * 64 + r16k + 16 * g) * 8) =
            make_uint4(pk[0], pk[1], pk[2], pk[3]);
      }
    }
    pn[q][lane] = s;
    __syncthreads();
    if (q == 0) mnorm[k] = pn[0][lane] + pn[1][lane] + pn[2][lane] + pn[3][lane];
  } else {
    const int r = bid - 8;
    float s = 0.f, sd = 0.f;
    #pragma unroll
    for (int i = 0; i < 4; ++i) {
      const int idx = r * 1024 + i * 256 + tid;
      const float4 a = Xh[idx];
      const float4 c = X[idx];
      const float e0 = a.x - c.x, e1 = a.y - c.y, e2 = a.z - c.z, e3 = a.w - c.w;
      s += e0 * e0 + e1 * e1 + e2 * e2 + e3 * e3;
    }
    if (tid < 128) {
      const float4 dd = Dh[r * 128 + tid];
      sd = dd.x + dd.y + dd.z + dd.w;
    }
    #pragma unroll
    for (int off = 32; off > 0; off >>= 1) {
      s  += __shfl_down(s, off);
      sd += __shfl_down(sd, off);
    }
    if (lane == 0) { ps[q] = s; ps[4 + q] = sd; }
    __syncthreads();
    if (tid == 0) {
      recp[r] = ps[0] + ps[1] + ps[2] + ps[3];
      dhp[r]  = ps[4] + ps[5] + ps[6] + ps[7];
    }
  }
}

// ---------------------------------------------------------------------------
// Kernel 2: main. 512 threads (8 waves), one block per (b, t-tile of 128),
// grid 256. R2's proven chunked staging (float4 -> LDS scratch -> pack,
// 16 live temps, no spill), then R2/R7's MFMA phase, then R7's verified
// last-block combine (counter zeroed by prep each launch).
// ---------------------------------------------------------------------------
__global__ __launch_bounds__(512, 2) void edm_main(
    const float* __restrict__ H, const unsigned short* __restrict__ MtF,
    const float* __restrict__ mnorm, const float* __restrict__ recp,
    const float* __restrict__ dhp, float* __restrict__ d2part,
    unsigned* __restrict__ counter, float* __restrict__ out) {
  __shared__ __align__(16) float scratch[64][132];         // fp32 staging (padded)
  __shared__ __align__(16) unsigned short Hbf[128 * 256];  // [t][d] bf16, swizzled
  __shared__ float hsumP[4][128];
  __shared__ float wmin[8][128];
  __shared__ float red[12];
  __shared__ float bsum[2];
  __shared__ int   islast;

  const int tid  = threadIdx.x;
  const int wv   = tid >> 6;       // wave 0..7
  const int l    = tid & 63;
  const int tcol = tid & 127;      // owned t column
  const int q    = tid >> 7;       // d row-group 0..3
  const int r16  = l & 15;
  const int g    = l >> 4;
  const unsigned sel = 0x07060302u;

  const int b  = blockIdx.x >> 2;
  const int t0 = (blockIdx.x & 3) << 7;
  const float* Hb = H + (size_t)b * DD * TT + t0;

  // ---- staging: 4 chunks of 64 d-rows x 128 t (R2's proven path) ----
  float hacc = 0.f;
  char* rowp = (char*)Hbf + tcol * 512;
  const int swz = (tcol & 7) << 4;
  for (int ch = 0; ch < 4; ++ch) {
    #pragma unroll
    for (int ii = 0; ii < 4; ++ii) {           // coalesced global -> fp32 scratch
      const int f  = ii * 512 + tid;
      const int dl = f >> 5;
      const int t4 = (f & 31) << 2;
      *(float4*)&scratch[dl][t4] =
          *(const float4*)(Hb + (size_t)(ch * 64 + dl) * TT + t4);
    }
    __syncthreads();
    unsigned pk[8];
    #pragma unroll
    for (int jj = 0; jj < 8; ++jj) {           // column read, pack
      const float x0 = scratch[q * 16 + 2 * jj + 0][tcol];
      const float x1 = scratch[q * 16 + 2 * jj + 1][tcol];
      hacc += x0 * x0 + x1 * x1;
      pk[jj] = pkbf(x0, x1, sel);
    }
    const int dbase2 = ch * 128 + q * 32;
    *(uint4*)(rowp + ((dbase2 +  0) ^ swz)) = make_uint4(pk[0], pk[1], pk[2], pk[3]);
    *(uint4*)(rowp + ((dbase2 + 16) ^ swz)) = make_uint4(pk[4], pk[5], pk[6], pk[7]);
    __syncthreads();
  }
  hsumP[q][tcol] = hacc;                       // unique slot per thread

  // ---- MFMA phase: wave wv owns k in [wv*64, +64) ----
  f4 acc[4][8];
  #pragma unroll
  for (int kt = 0; kt < 4; ++kt)
    #pragma unroll
    for (int tn = 0; tn < 8; ++tn)
      acc[kt][tn] = (f4){0.f, 0.f, 0.f, 0.f};
  asm volatile("s_nop 1" : ACCLIST8(acc));     // VALU-write -> MFMA-read-C guard

  #pragma unroll
  for (int ds = 0; ds < 8; ++ds) {             // 8 x K=32 over d
    bf8 afr[4];
    #pragma unroll
    for (int kt = 0; kt < 4; ++kt)             // coalesced 1 KB fragment chunks
      afr[kt] = *(const bf8*)(MtF + (((size_t)(wv * 4 + kt) * 8 + ds) * 64 + l) * 8);
    #pragma unroll
    for (int tn = 0; tn < 8; ++tn) {
      const int t = tn * 16 + r16;
      const bf8 bfr = *(const bf8*)((const char*)Hbf + t * 512 +
                                    ((ds * 64 + g * 16) ^ ((t & 7) << 4)));
      MFMA(acc[0][tn], afr[0], bfr);
      MFMA(acc[1][tn], afr[1], bfr);
      MFMA(acc[2][tn], afr[2], bfr);
      MFMA(acc[3][tn], afr[3], bfr);
    }
  }
  asm volatile("s_nop 7\n\ts_nop 7" : ACCLIST8(acc));  // MFMA-write -> VALU guard

  // fold: k = wv*64 + kt*16 + 4*g + rr (C/D map: col=lane&15, row=4*(l>>4)+reg)
  float rmin[8] = {3.0e38f, 3.0e38f, 3.0e38f, 3.0e38f,
                   3.0e38f, 3.0e38f, 3.0e38f, 3.0e38f};
  #pragma unroll
  for (int kt = 0; kt < 4; ++kt) {
    const f4 mn = *(const f4*)(mnorm + wv * 64 + kt * 16 + g * 4);
    #pragma unroll
    for (int tn = 0; tn < 8; ++tn) {
      #pragma unroll
      for (int rr = 0; rr < 4; ++rr)
        rmin[tn] = fminf(rmin[tn], mn[rr] - 2.f * acc[kt][tn][rr]);
    }
  }
  #pragma unroll
  for (int tn = 0; tn < 8; ++tn) {
    rmin[tn] = fminf(rmin[tn], __shfl_xor(rmin[tn], 16));
    rmin[tn] = fminf(rmin[tn], __shfl_xor(rmin[tn], 32));
  }
  if (g == 0) {
    #pragma unroll
    for (int tn = 0; tn < 8; ++tn) wmin[wv][tn * 16 + r16] = rmin[tn];
  }
  __syncthreads();

  if (tid < 128) {
    float m = wmin[0][tid];
    #pragma unroll
    for (int w = 1; w < 8; ++w) m = fminf(m, wmin[w][tid]);
    float v = m + hsumP[0][tid] + hsumP[1][tid] + hsumP[2][tid] + hsumP[3][tid];
    #pragma unroll
    for (int off = 32; off > 0; off >>= 1) v += __shfl_down(v, off);
    if ((tid & 63) == 0) bsum[tid >> 6] = v;
  }
  __syncthreads();
  if (tid == 0) {
    __hip_atomic_store(&d2part[blockIdx.x], bsum[0] + bsum[1],
                       __ATOMIC_RELEASE, __HIP_MEMORY_SCOPE_AGENT);
    islast = (__hip_atomic_fetch_add(counter, 1u, __ATOMIC_ACQ_REL,
                                     __HIP_MEMORY_SCOPE_AGENT) == 255u) ? 1 : 0;
  }
  __syncthreads();

  if (islast) {
    float a = 0.f, r = 0.f, dh = 0.f;
    if (tid < 256) {
      a = __hip_atomic_load(&d2part[tid], __ATOMIC_RELAXED,
                            __HIP_MEMORY_SCOPE_AGENT);
      if (tid < 64) { r = recp[tid]; dh = dhp[tid]; }
    }
    #pragma unroll
    for (int off = 32; off > 0; off >>= 1) {
      a  += __shfl_down(a, off);
      r  += __shfl_down(r, off);
      dh += __shfl_down(dh, off);
    }
    if (tid < 256 && (tid & 63) == 0) {
      const int w = tid >> 6;
      red[w] = a; red[4 + w] = r; red[8 + w] = dh;
    }
    __syncthreads();
    if (tid == 0) {
      const float d2sum  = red[0] + red[1] + red[2] + red[3];
      const float recsum = red[4] + red[5] + red[6] + red[7];
      const float dhsum  = red[8] + red[9] + red[10] + red[11];
      // loss = recsum/262144 + 0.25*2*d2sum/8388608 - 0.1*dhsum/32768
      out[0] = recsum * (1.f / 262144.f)
             + d2sum  * (1.f / 16777216.f)
             - 0.1f * dhsum * (1.f / 32768.f);
    }
  }
}

extern "C" void kernel_launch(void* const* d_in, const int* in_sizes, int n_in,
                              void* d_out, int out_size, void* d_ws, size_t ws_size,
                              hipStream_t stream) {
  const float* Xh = (const float*)d_in[0];   // [64,8,512]
  const float* X  = (const float*)d_in[1];   // [64,8,512]
  const float* H  = (const float*)d_in[2];   // [64,256,512]
  const float* M  = (const float*)d_in[3];   // [256,512]
  const float* Dh = (const float*)d_in[4];   // [64,512]
  float* out = (float*)d_out;

  unsigned short* MtF = (unsigned short*)d_ws;                     // 256 KiB
  float* mnorm = (float*)((char*)d_ws + (size_t)KK * DD * 2);      // 512 f
  float* recp  = mnorm + KK;                                       // 64 f
  float* dhp   = recp + 64;                                        // 64 f
  float* d2p   = dhp + 64;                                         // 256 f
  unsigned* counter = (unsigned*)(d2p + 256);                      // 1 u32

  edm_prep<<<72, 256, 0, stream>>>(M, (const float4*)Xh, (const float4*)X,
                                   (const float4*)Dh, MtF, mnorm, recp, dhp,
                                   counter);
  edm_main<<<NB * (TT / 128), 512, 0, stream>>>(H, MtF, mnorm, recp, dhp,
                                                d2p, counter, out);
}